// Round 2
// baseline (138.799 us; speedup 1.0000x reference)
//
#include <hip/hip_runtime.h>
#include <hip/hip_bf16.h>

#define NODES 50000
#define NA    65
#define NDEG  32

// ws layout (f32): [0..15] Wc0, [16..31] Wc1, [32..47] bc,
//                  [48..559] W2f (row-major j*32+k), [560..591] b2f
//                  [600] dtype flag (int): 1 = bf16 inputs/outputs, 0 = f32

// ---------- dtype probe: score both interpretations of b2 ----------
__global__ void probe_kernel(const void* __restrict__ b2, int* __restrict__ flag) {
    if (threadIdx.x != 0 || blockIdx.x != 0) return;
    const unsigned* w = (const unsigned*)b2;   // 32 bytes: safe for bf16(64B) & f32(128B)
    int okf = 1, okb = 1;
    for (int i = 0; i < 8; ++i) {
        unsigned u = w[i];
        float f = __uint_as_float(u);
        float a = fabsf(f);
        if (!(f == f) || a > 0.30f || (f != 0.0f && a < 1e-6f)) okf = 0;
        float lo = __uint_as_float(u << 16);
        float hi = __uint_as_float(u & 0xffff0000u);
        float al = fabsf(lo), ah = fabsf(hi);
        if (!(lo == lo) || al > 0.30f || (lo != 0.0f && al < 1e-6f)) okb = 0;
        if (!(hi == hi) || ah > 0.30f || (hi != 0.0f && ah < 1e-6f)) okb = 0;
    }
    *flag = okb ? 1 : 0;   // prefer bf16 if (improbably) both pass; else f32
}

// dtype-flag-aware scalar weight load
static __device__ __forceinline__ float ldv(const void* p, int i, int isbf) {
    if (isbf) {
        unsigned short s = ((const unsigned short*)p)[i];
        return __uint_as_float(((unsigned)s) << 16);
    }
    return ((const float*)p)[i];
}

__global__ void prep_kernel(const void* __restrict__ W_se,
                            const void* __restrict__ b_se,
                            const void* __restrict__ W1,
                            const void* __restrict__ b1,
                            const void* __restrict__ W2,
                            const void* __restrict__ b2,
                            float* __restrict__ ws) {
    int t = threadIdx.x;  // 256 threads, 1 block
    int isbf = ((const int*)ws)[600];
    if (t < 32) {
        // Wc[c][j] = sum_e W_se[c][e] * W1[e][j]   (W_se (2,32), W1 (32,16))
        int c = t >> 4, j = t & 15;
        float s = 0.0f;
        for (int e = 0; e < 32; ++e)
            s = fmaf(ldv(W_se, c * 32 + e, isbf), ldv(W1, e * 16 + j, isbf), s);
        ws[c * 16 + j] = s;
    } else if (t < 48) {
        // bc[j] = b_se @ W1 + b1
        int j = t - 32;
        float s = ldv(b1, j, isbf);
        for (int e = 0; e < 32; ++e)
            s = fmaf(ldv(b_se, e, isbf), ldv(W1, e * 16 + j, isbf), s);
        ws[32 + j] = s;
    }
    for (int i = t; i < 512; i += 256) ws[48 + i] = ldv(W2, i, isbf);  // W2 (16,32)
    if (t < 32) ws[560 + t] = ldv(b2, t, isbf);
}

static __device__ __forceinline__ unsigned short f2bf_rne(float f) {
    unsigned u = __float_as_uint(f);
    u += 0x7fffu + ((u >> 16) & 1u);
    return (unsigned short)(u >> 16);
}

// shared math: given r0,r1 and reg weights, update vmax[8]
static __device__ __forceinline__ void mlp_step(float r0, float r1,
                                                const float* Wc0, const float* Wc1,
                                                const float* bc, const float* W2l,
                                                const float* b2l, float* vmax) {
    float h1[16];
#pragma unroll
    for (int j = 0; j < 16; ++j)
        h1[j] = fmaxf(0.0f, fmaf(r0, Wc0[j], fmaf(r1, Wc1[j], bc[j])));
#pragma unroll
    for (int i = 0; i < 8; ++i) {
        float s = b2l[i];
#pragma unroll
        for (int j = 0; j < 16; ++j) s = fmaf(h1[j], W2l[j * 8 + i], s);
        vmax[i] = fmaxf(vmax[i], s);  // relu folded: vmax starts at 0
    }
}

static __device__ __forceinline__ void load_weights(const float* ws, int k0,
                                                    float* Wc0, float* Wc1, float* bc,
                                                    float* W2l, float* b2l) {
    const float4* wsv = (const float4*)ws;
#pragma unroll
    for (int j = 0; j < 4; ++j) {
        float4 x = wsv[j];
        Wc0[4*j] = x.x; Wc0[4*j+1] = x.y; Wc0[4*j+2] = x.z; Wc0[4*j+3] = x.w;
        float4 y = wsv[4 + j];
        Wc1[4*j] = y.x; Wc1[4*j+1] = y.y; Wc1[4*j+2] = y.z; Wc1[4*j+3] = y.w;
        float4 z = wsv[8 + j];
        bc[4*j] = z.x; bc[4*j+1] = z.y; bc[4*j+2] = z.z; bc[4*j+3] = z.w;
    }
#pragma unroll
    for (int j = 0; j < 16; ++j) {
        const float4* p = (const float4*)(ws + 48 + j * 32 + k0);
        float4 x = p[0], y = p[1];
        W2l[j*8+0] = x.x; W2l[j*8+1] = x.y; W2l[j*8+2] = x.z; W2l[j*8+3] = x.w;
        W2l[j*8+4] = y.x; W2l[j*8+5] = y.y; W2l[j*8+6] = y.z; W2l[j*8+7] = y.w;
    }
    const float4* p = (const float4*)(ws + 560 + k0);
    float4 x = p[0], y = p[1];
    b2l[0] = x.x; b2l[1] = x.y; b2l[2] = x.z; b2l[3] = x.w;
    b2l[4] = y.x; b2l[5] = y.y; b2l[6] = y.z; b2l[7] = y.w;
}

// ---------------- bf16 input/output variant ----------------
__global__ __launch_bounds__(256) void pool_kernel_bf16(
    const void* __restrict__ corr, const int* __restrict__ nei,
    const float* __restrict__ ws, void* __restrict__ out) {
    if (((const int*)ws)[600] != 1) return;
    int tid = blockIdx.x * 256 + threadIdx.x;
    if (tid >= NODES * 4) return;
    int n = tid >> 2, k0 = (tid & 3) * 8;

    float Wc0[16], Wc1[16], bc[16], W2l[128], b2l[8];
    load_weights(ws, k0, Wc0, Wc1, bc, W2l, b2l);

    float vmax[8];
#pragma unroll
    for (int i = 0; i < 8; ++i) vmax[i] = 0.0f;

    const unsigned* corrw = (const unsigned*)corr + (size_t)n * NA;  // bf16 pair/word
    const int* neip = nei + (size_t)n * NDEG * 3 + 1;

    for (int c = 0; c < 8; ++c) {
        int aidx[4];
#pragma unroll
        for (int u = 0; u < 4; ++u) aidx[u] = neip[(c * 4 + u) * 3];
        unsigned relb[4];
#pragma unroll
        for (int u = 0; u < 4; ++u) relb[u] = corrw[aidx[u]];
#pragma unroll
        for (int u = 0; u < 4; ++u) {
            float r0 = __uint_as_float(relb[u] << 16);
            float r1 = __uint_as_float(relb[u] & 0xffff0000u);
            mlp_step(r0, r1, Wc0, Wc1, bc, W2l, b2l, vmax);
        }
    }

    uint4 pk;
    pk.x = (unsigned)f2bf_rne(vmax[0]) | ((unsigned)f2bf_rne(vmax[1]) << 16);
    pk.y = (unsigned)f2bf_rne(vmax[2]) | ((unsigned)f2bf_rne(vmax[3]) << 16);
    pk.z = (unsigned)f2bf_rne(vmax[4]) | ((unsigned)f2bf_rne(vmax[5]) << 16);
    pk.w = (unsigned)f2bf_rne(vmax[6]) | ((unsigned)f2bf_rne(vmax[7]) << 16);
    *(uint4*)((unsigned short*)out + (size_t)n * 32 + k0) = pk;
}

// ---------------- f32 input/output variant ----------------
__global__ __launch_bounds__(256) void pool_kernel_f32(
    const void* __restrict__ corr, const int* __restrict__ nei,
    const float* __restrict__ ws, void* __restrict__ out) {
    if (((const int*)ws)[600] != 0) return;
    int tid = blockIdx.x * 256 + threadIdx.x;
    if (tid >= NODES * 4) return;
    int n = tid >> 2, k0 = (tid & 3) * 8;

    float Wc0[16], Wc1[16], bc[16], W2l[128], b2l[8];
    load_weights(ws, k0, Wc0, Wc1, bc, W2l, b2l);

    float vmax[8];
#pragma unroll
    for (int i = 0; i < 8; ++i) vmax[i] = 0.0f;

    const float2* corrf = (const float2*)corr + (size_t)n * NA;  // (r0,r1) per slot
    const int* neip = nei + (size_t)n * NDEG * 3 + 1;

    for (int c = 0; c < 8; ++c) {
        int aidx[4];
#pragma unroll
        for (int u = 0; u < 4; ++u) aidx[u] = neip[(c * 4 + u) * 3];
        float2 rel[4];
#pragma unroll
        for (int u = 0; u < 4; ++u) rel[u] = corrf[aidx[u]];
#pragma unroll
        for (int u = 0; u < 4; ++u)
            mlp_step(rel[u].x, rel[u].y, Wc0, Wc1, bc, W2l, b2l, vmax);
    }

    float4 a = make_float4(vmax[0], vmax[1], vmax[2], vmax[3]);
    float4 b = make_float4(vmax[4], vmax[5], vmax[6], vmax[7]);
    float* op = (float*)out + (size_t)n * 32 + k0;
    ((float4*)op)[0] = a;
    ((float4*)op)[1] = b;
}

extern "C" void kernel_launch(void* const* d_in, const int* in_sizes, int n_in,
                              void* d_out, int out_size, void* d_ws, size_t ws_size,
                              hipStream_t stream) {
    const void* corr = d_in[0];
    const int*  nei  = (const int*)d_in[1];
    // d_in[2] = lstm_state: unused by the output
    const void* W_se = d_in[3];
    const void* b_se = d_in[4];
    const void* W1   = d_in[5];
    const void* b1   = d_in[6];
    const void* W2   = d_in[7];
    const void* b2   = d_in[8];
    float* ws = (float*)d_ws;

    hipLaunchKernelGGL(probe_kernel, dim3(1), dim3(64), 0, stream, b2, (int*)ws + 600);
    hipLaunchKernelGGL(prep_kernel, dim3(1), dim3(256), 0, stream,
                       W_se, b_se, W1, b1, W2, b2, ws);
    int total = NODES * 4;
    int blocks = (total + 255) / 256;
    hipLaunchKernelGGL(pool_kernel_bf16, dim3(blocks), dim3(256), 0, stream,
                       corr, nei, ws, d_out);
    hipLaunchKernelGGL(pool_kernel_f32, dim3(blocks), dim3(256), 0, stream,
                       corr, nei, ws, d_out);
}